// Round 3
// baseline (1051.084 us; speedup 1.0000x reference)
//
#include <hip/hip_runtime.h>
#include <hip/hip_bf16.h>

// Problem constants (match reference setup_inputs)
#define NB 4096   // batch
#define TT 128    // seq len
#define EE 256    // embed dim
#define HH 64     // head dim

typedef __attribute__((ext_vector_type(8))) short bf16x8;
typedef __attribute__((ext_vector_type(4))) float f32x4;
typedef __attribute__((ext_vector_type(4))) unsigned short u16x4;

__device__ __forceinline__ unsigned short f2bf(float f) {
  union { float f; unsigned u; } c; c.f = f;
  return (unsigned short)((c.u + 0x7fffu + ((c.u >> 16) & 1u)) >> 16);
}

// Packed f32x4 -> 4 bf16 via v_cvt_pk_bf16_f32 (RNE)
__device__ __forceinline__ u16x4 pk4(f32x4 v) {
  union { u16x4 s; __hip_bfloat162 h[2]; } u;
  u.h[0] = __float22bfloat162_rn(make_float2(v[0], v[1]));
  u.h[1] = __float22bfloat162_rn(make_float2(v[2], v[3]));
  return u.s;
}

__device__ __forceinline__ bf16x8 cvt8(f32x4 a, f32x4 b) {
  union { bf16x8 v; __hip_bfloat162 h[4]; } u;
  u.h[0] = __float22bfloat162_rn(make_float2(a[0], a[1]));
  u.h[1] = __float22bfloat162_rn(make_float2(a[2], a[3]));
  u.h[2] = __float22bfloat162_rn(make_float2(b[0], b[1]));
  u.h[3] = __float22bfloat162_rn(make_float2(b[2], b[3]));
  return u.v;
}

// ---- XOR-swizzled LDS layouts (no padding; keeps ds_read_b128 conflict-free)
__device__ __forceinline__ int qk_idx(int t, int h) {   // Q/K: [t=128][h=64]
  return t * 64 + ((((h >> 3) ^ t) & 7) << 3) + (h & 7);
}
__device__ __forceinline__ int p_idx(int t, int c) {    // P: [t=128][c=128]
  return t * 128 + ((((c >> 3) ^ t) & 15) << 3) + (c & 7);
}
__device__ __forceinline__ int vt_idx(int h, int t) {   // V^T: [h=64][t=128]
  return h * 128 + ((((t >> 3) ^ h) & 15) << 3) + (t & 7);
}

// wt[n][e] = W_{n/64}[e][n%64], bf16, B^T-row-contiguous for the MFMA B operand
__global__ void prep_w(const float* __restrict__ wq, const float* __restrict__ wk,
                       const float* __restrict__ wv, unsigned short* __restrict__ wt) {
  int n = blockIdx.x;    // 0..191
  int e = threadIdx.x;   // 0..255
  const float* w = (n < 64) ? wq : (n < 128) ? wk : wv;
  wt[n * EE + e] = f2bf(w[e * HH + (n & 63)]);
}

__global__ __launch_bounds__(256, 3)
void attn_fused(const float* __restrict__ x, const unsigned short* __restrict__ wt,
                float* __restrict__ out) {
  // 49,152 B total -> 3 blocks/CU.
  __shared__ __align__(16) unsigned short sbuf[24576];
  unsigned short* qbuf = sbuf;           // Q [128][64]  (16 KB)
  unsigned short* kbuf = sbuf + 8192;    // K [128][64]  (16 KB)
  unsigned short* vbuf = sbuf + 16384;   // V^T [64][128](16 KB)
  unsigned short* pbuf = sbuf;           // P [128][128] aliases Q+K after barrier

  const int b    = blockIdx.x;
  const int tid  = threadIdx.x;
  const int w    = tid >> 6;    // wave 0..3
  const int lane = tid & 63;
  const int quad = lane >> 4;   // 0..3
  const int l16  = lane & 15;
  const int m0   = 32 * w;      // this wave owns rows [m0, m0+32)

  const float* __restrict__ xb = x + (size_t)b * TT * EE;
  const float* xrow0 = xb + (m0 + l16) * EE + quad * 8;
  const float* xrow1 = xb + (m0 + 16 + l16) * EE + quad * 8;

  // ================ Phase 1, pass A: [Q|K] = x @ [Wq|Wk]  (N=128, 16 accs)
  {
    f32x4 acc[8][2];
#pragma unroll
    for (int nt = 0; nt < 8; ++nt)
#pragma unroll
      for (int mt = 0; mt < 2; ++mt)
        acc[nt][mt] = (f32x4){0.f, 0.f, 0.f, 0.f};

    // depth-2 ping-pong pipeline over kc (8 chunks of 32)
    f32x4 nf0[4], nf1[4];
    nf0[0] = *(const f32x4*)(xrow0);      nf0[1] = *(const f32x4*)(xrow0 + 4);
    nf0[2] = *(const f32x4*)(xrow1);      nf0[3] = *(const f32x4*)(xrow1 + 4);
    nf1[0] = *(const f32x4*)(xrow0 + 32); nf1[1] = *(const f32x4*)(xrow0 + 36);
    nf1[2] = *(const f32x4*)(xrow1 + 32); nf1[3] = *(const f32x4*)(xrow1 + 36);

#pragma unroll 1
    for (int kc = 0; kc < 8; kc += 2) {
      bf16x8 a0 = cvt8(nf0[0], nf0[1]);
      bf16x8 a1 = cvt8(nf0[2], nf0[3]);
      if (kc + 2 < 8) {
        const float* p0 = xrow0 + (kc + 2) * 32;
        const float* p1 = xrow1 + (kc + 2) * 32;
        nf0[0] = *(const f32x4*)(p0); nf0[1] = *(const f32x4*)(p0 + 4);
        nf0[2] = *(const f32x4*)(p1); nf0[3] = *(const f32x4*)(p1 + 4);
      }
#pragma unroll
      for (int nt = 0; nt < 8; ++nt) {
        bf16x8 bfr = *(const bf16x8*)(wt + (nt * 16 + l16) * EE + kc * 32 + quad * 8);
        acc[nt][0] = __builtin_amdgcn_mfma_f32_16x16x32_bf16(a0, bfr, acc[nt][0], 0, 0, 0);
        acc[nt][1] = __builtin_amdgcn_mfma_f32_16x16x32_bf16(a1, bfr, acc[nt][1], 0, 0, 0);
      }
      a0 = cvt8(nf1[0], nf1[1]);
      a1 = cvt8(nf1[2], nf1[3]);
      if (kc + 3 < 8) {
        const float* p0 = xrow0 + (kc + 3) * 32;
        const float* p1 = xrow1 + (kc + 3) * 32;
        nf1[0] = *(const f32x4*)(p0); nf1[1] = *(const f32x4*)(p0 + 4);
        nf1[2] = *(const f32x4*)(p1); nf1[3] = *(const f32x4*)(p1 + 4);
      }
#pragma unroll
      for (int nt = 0; nt < 8; ++nt) {
        bf16x8 bfr = *(const bf16x8*)(wt + (nt * 16 + l16) * EE + (kc + 1) * 32 + quad * 8);
        acc[nt][0] = __builtin_amdgcn_mfma_f32_16x16x32_bf16(a0, bfr, acc[nt][0], 0, 0, 0);
        acc[nt][1] = __builtin_amdgcn_mfma_f32_16x16x32_bf16(a1, bfr, acc[nt][1], 0, 0, 0);
      }
    }

    // Scatter Q (nt 0..3) / K (nt 4..7) to LDS. C-layout: row=rbase+r, col=nt*16+l16.
#pragma unroll
    for (int nt = 0; nt < 8; ++nt) {
      int col = (nt & 3) * 16 + l16;     // 0..63 within Q or K
      unsigned short* dst = (nt < 4) ? qbuf : kbuf;
#pragma unroll
      for (int mt = 0; mt < 2; ++mt) {
        int rbase = m0 + 16 * mt + 4 * quad;
        u16x4 pv = pk4(acc[nt][mt]);
#pragma unroll
        for (int r = 0; r < 4; ++r)
          dst[qk_idx(rbase + r, col)] = pv[r];
      }
    }
  }

  // ================ Phase 1, pass B: V = x @ Wv  (N=64, 8 accs; x re-read, L3-hot)
  {
    f32x4 acc[4][2];
#pragma unroll
    for (int j = 0; j < 4; ++j)
#pragma unroll
      for (int mt = 0; mt < 2; ++mt)
        acc[j][mt] = (f32x4){0.f, 0.f, 0.f, 0.f};

    f32x4 nf0[4], nf1[4];
    nf0[0] = *(const f32x4*)(xrow0);      nf0[1] = *(const f32x4*)(xrow0 + 4);
    nf0[2] = *(const f32x4*)(xrow1);      nf0[3] = *(const f32x4*)(xrow1 + 4);
    nf1[0] = *(const f32x4*)(xrow0 + 32); nf1[1] = *(const f32x4*)(xrow0 + 36);
    nf1[2] = *(const f32x4*)(xrow1 + 32); nf1[3] = *(const f32x4*)(xrow1 + 36);

#pragma unroll 1
    for (int kc = 0; kc < 8; kc += 2) {
      bf16x8 a0 = cvt8(nf0[0], nf0[1]);
      bf16x8 a1 = cvt8(nf0[2], nf0[3]);
      if (kc + 2 < 8) {
        const float* p0 = xrow0 + (kc + 2) * 32;
        const float* p1 = xrow1 + (kc + 2) * 32;
        nf0[0] = *(const f32x4*)(p0); nf0[1] = *(const f32x4*)(p0 + 4);
        nf0[2] = *(const f32x4*)(p1); nf0[3] = *(const f32x4*)(p1 + 4);
      }
#pragma unroll
      for (int j = 0; j < 4; ++j) {
        bf16x8 bfr = *(const bf16x8*)(wt + ((8 + j) * 16 + l16) * EE + kc * 32 + quad * 8);
        acc[j][0] = __builtin_amdgcn_mfma_f32_16x16x32_bf16(a0, bfr, acc[j][0], 0, 0, 0);
        acc[j][1] = __builtin_amdgcn_mfma_f32_16x16x32_bf16(a1, bfr, acc[j][1], 0, 0, 0);
      }
      a0 = cvt8(nf1[0], nf1[1]);
      a1 = cvt8(nf1[2], nf1[3]);
      if (kc + 3 < 8) {
        const float* p0 = xrow0 + (kc + 3) * 32;
        const float* p1 = xrow1 + (kc + 3) * 32;
        nf1[0] = *(const f32x4*)(p0); nf1[1] = *(const f32x4*)(p0 + 4);
        nf1[2] = *(const f32x4*)(p1); nf1[3] = *(const f32x4*)(p1 + 4);
      }
#pragma unroll
      for (int j = 0; j < 4; ++j) {
        bf16x8 bfr = *(const bf16x8*)(wt + ((8 + j) * 16 + l16) * EE + (kc + 1) * 32 + quad * 8);
        acc[j][0] = __builtin_amdgcn_mfma_f32_16x16x32_bf16(a0, bfr, acc[j][0], 0, 0, 0);
        acc[j][1] = __builtin_amdgcn_mfma_f32_16x16x32_bf16(a1, bfr, acc[j][1], 0, 0, 0);
      }
    }

    // Scatter V^T[h][t]: lane's 4 consecutive rows (t) -> one 8B packed write.
#pragma unroll
    for (int j = 0; j < 4; ++j) {
      int col = j * 16 + l16;            // h
#pragma unroll
      for (int mt = 0; mt < 2; ++mt) {
        int rbase = m0 + 16 * mt + 4 * quad;
        *(u16x4*)(vbuf + vt_idx(col, rbase)) = pk4(acc[j][mt]);
      }
    }
  }
  __syncthreads();

  // ================ Phase 2: S = Q K^T / 8, causal, softmax -> P (bf16, LDS)
  const int ntS = 2 * w + 2;
  f32x4 sacc[8][2];
#pragma unroll
  for (int nt = 0; nt < 8; ++nt)
#pragma unroll
    for (int mt = 0; mt < 2; ++mt)
      sacc[nt][mt] = (f32x4){0.f, 0.f, 0.f, 0.f};

#pragma unroll
  for (int kk = 0; kk < 2; ++kk) {
    bf16x8 aq[2];
    aq[0] = *(const bf16x8*)(qbuf + qk_idx(m0 + l16, kk * 32 + quad * 8));
    aq[1] = *(const bf16x8*)(qbuf + qk_idx(m0 + 16 + l16, kk * 32 + quad * 8));
#pragma unroll
    for (int nt = 0; nt < 8; ++nt) {
      if (nt < ntS) {   // wave-uniform
        bf16x8 bk = *(const bf16x8*)(kbuf + qk_idx(nt * 16 + l16, kk * 32 + quad * 8));
        sacc[nt][0] = __builtin_amdgcn_mfma_f32_16x16x32_bf16(aq[0], bk, sacc[nt][0], 0, 0, 0);
        sacc[nt][1] = __builtin_amdgcn_mfma_f32_16x16x32_bf16(aq[1], bk, sacc[nt][1], 0, 0, 0);
      }
    }
  }
  __syncthreads();  // all waves done reading Q/K -> region reusable as P

  const float scale = 0.125f;  // 1/sqrt(64)
#pragma unroll
  for (int mt = 0; mt < 2; ++mt) {
#pragma unroll
    for (int r = 0; r < 4; ++r) {
      int row = m0 + 16 * mt + 4 * quad + r;
      float mx = -3.0e38f;
#pragma unroll
      for (int nt = 0; nt < 8; ++nt) {
        if (nt < ntS) {
          int c = nt * 16 + l16;
          float s = (c <= row) ? sacc[nt][mt][r] * scale : -3.0e38f;
          sacc[nt][mt][r] = s;
          mx = fmaxf(mx, s);
        }
      }
#pragma unroll
      for (int off = 1; off < 16; off <<= 1) mx = fmaxf(mx, __shfl_xor(mx, off, 64));
      float sum = 0.f;
#pragma unroll
      for (int nt = 0; nt < 8; ++nt) {
        if (nt < ntS) {
          float e = __expf(sacc[nt][mt][r] - mx);
          sacc[nt][mt][r] = e;
          sum += e;
        }
      }
#pragma unroll
      for (int off = 1; off < 16; off <<= 1) sum += __shfl_xor(sum, off, 64);
      float inv = 1.0f / sum;
#pragma unroll
      for (int nt = 0; nt < 8; ++nt) {
        if (nt < ntS)
          pbuf[p_idx(row, nt * 16 + l16)] = f2bf(sacc[nt][mt][r] * inv);
      }
    }
  }
  // No barrier: wave w reads only its own P rows below; V^T synced after phase 1.

  // ================ Phase 3: out = P @ V   (K=128, causal-clipped)
  f32x4 oacc[4][2];
#pragma unroll
  for (int nt = 0; nt < 4; ++nt)
#pragma unroll
    for (int mt = 0; mt < 2; ++mt)
      oacc[nt][mt] = (f32x4){0.f, 0.f, 0.f, 0.f};

  for (int ks = 0; ks <= w; ++ks) {
    bf16x8 ap[2];
    ap[0] = *(const bf16x8*)(pbuf + p_idx(m0 + l16, ks * 32 + quad * 8));
    ap[1] = *(const bf16x8*)(pbuf + p_idx(m0 + 16 + l16, ks * 32 + quad * 8));
#pragma unroll
    for (int nt = 0; nt < 4; ++nt) {
      bf16x8 bv = *(const bf16x8*)(vbuf + vt_idx(nt * 16 + l16, ks * 32 + quad * 8));
      oacc[nt][0] = __builtin_amdgcn_mfma_f32_16x16x32_bf16(ap[0], bv, oacc[nt][0], 0, 0, 0);
      oacc[nt][1] = __builtin_amdgcn_mfma_f32_16x16x32_bf16(ap[1], bv, oacc[nt][1], 0, 0, 0);
    }
  }

  float* __restrict__ ob = out + (size_t)b * TT * HH;
#pragma unroll
  for (int mt = 0; mt < 2; ++mt) {
#pragma unroll
    for (int r = 0; r < 4; ++r) {
      int row = m0 + 16 * mt + 4 * quad + r;
#pragma unroll
      for (int nt = 0; nt < 4; ++nt)
        ob[row * HH + nt * 16 + l16] = oacc[nt][mt][r];
    }
  }
}

extern "C" void kernel_launch(void* const* d_in, const int* in_sizes, int n_in,
                              void* d_out, int out_size, void* d_ws, size_t ws_size,
                              hipStream_t stream) {
  const float* x  = (const float*)d_in[0];
  const float* wq = (const float*)d_in[1];
  const float* wk = (const float*)d_in[2];
  const float* wv = (const float*)d_in[3];
  unsigned short* wt = (unsigned short*)d_ws;  // 192*256*2 = 98304 B
  float* outp = (float*)d_out;

  prep_w<<<dim3(192), dim3(256), 0, stream>>>(wq, wk, wv, wt);
  attn_fused<<<dim3(NB), dim3(256), 0, stream>>>(x, wt, outp);
}